// Round 8
// baseline (113.093 us; speedup 1.0000x reference)
//
#include <hip/hip_runtime.h>
#include <hip/hip_bf16.h>
#include <math.h>

// Cylindrical pooling: for each box, select first S in-radius points (ascending
// index), append box velocity, zero remaining slots.
//
// Exact f32 semantics: reference computes dis = sqrt_rn(dx*dx + dy*dy) (no FMA
// contraction; explicit _rn intrinsics) and tests dis <= r. sqrt_rn is
// monotone, so dis <= r  <=>  d2 <= T with T = max{x : sqrt_rn(x) <= r},
// found by a 64-lane ulp-window probe (validated bit-exact in R7).
//
// SINGLE fused kernel (R4's 3-dispatch adaptive = 24.6us was ~1/3 launch/gap
// overhead; R5 showed cross-block fences cost ~300us -> everything must be
// block-local): one block per box does count -> scan -> worklist -> emit.
//  - Tiered counting with early saturation exit: count groups [0,128), reduce,
//    stop if >= S hits (~93% of boxes); else widen to [128,512), [512,2048),
//    [2048,ngrp). No intra-tier barriers (16 waves count strided groups into
//    LDS), one barrier+reduce per tier. Overshoot < 4x needed work.
//  - Unsaturated boxes sweep their full range point-parallel across 16 waves;
//    all such blocks run concurrently on separate CUs.
// Distribution affects speed only, never correctness; worst case stays
// fully parallel (every block sweeps, ~all CUs busy).

#define MAXGRP 4096   // s_cnt LDS capacity (groups of 64 points)

__device__ __forceinline__ float box_radius(const float* __restrict__ b) {
    float hx = __fmul_rn(b[3], 0.5f);
    float hy = __fmul_rn(b[4], 0.5f);
    float nrm = __fsqrt_rn(__fadd_rn(__fmul_rn(hx, hx), __fmul_rn(hy, hy)));
    return __fmul_rn(nrm, 1.1f);   // GAMMA
}

// largest x with __fsqrt_rn(x) <= r, searched in a 64-ulp window around r*r.
// All 64 lanes participate (call under wave-uniform control flow).
// Bit order == float order for non-negative floats.
__device__ __forceinline__ float probe_T(float r, int lane) {
    int xb = __float_as_int(__fmul_rn(r, r));      // r >= 0 so xb >= 0
    int yb = xb + lane - 32; if (yb < 0) yb = 0;
    bool ok = __fsqrt_rn(__int_as_float(yb)) <= r; // monotone in yb
    unsigned long long mask = __ballot(ok);
    int hi = 63 - __clzll(mask);
    int tb = xb + hi - 32; if (tb < 0) tb = 0;
    return __int_as_float(tb);
}

__device__ __forceinline__ bool pt_in(float bx, float by, float T,
                                      float px, float py) {
    float dx = __fsub_rn(bx, px);
    float dy = __fsub_rn(by, py);
    float d2 = __fadd_rn(__fmul_rn(dx, dx), __fmul_rn(dy, dy));
    return d2 <= T;
}

// ---------------- fused kernel: one block per box ----------------
// Grid: M blocks x 1024 threads (16 waves).
__global__ __launch_bounds__(1024) void fused_kernel(
    const float* __restrict__ pts, const float* __restrict__ boxes,
    float* __restrict__ out, int N, int M, int S, int ngrp) {
    extern __shared__ int s_work[];        // S + 64 entries
    __shared__ int s_cnt[MAXGRP];
    __shared__ int s_tot[16];
    __shared__ int s_wsum[16];
    __shared__ int s_nwork;

    int m = blockIdx.x;
    int tid = threadIdx.x;
    int lane = tid & 63;
    int wid = tid >> 6;

    const float* b = boxes + (size_t)m * 9;
    float bx = b[0], by = b[1];
    float T = probe_T(box_radius(b), lane);    // wave-uniform, all waves
    float vx = b[7], vy = b[8];
    if (tid == 0) s_nwork = 0;

    // ---- tiered counting with early saturation exit ----
    int total = 0;
    int ngrp_eff = ngrp;
    int glo = 0;
    int tend[4] = {128, 512, 2048, ngrp};
    #pragma unroll 1
    for (int t = 0; t < 4; ++t) {
        int ghi = tend[t] < ngrp ? tend[t] : ngrp;
        if (ghi > glo) {                       // block-uniform
            int tloc = 0;
            for (int g = glo + wid; g < ghi; g += 16) {
                int p = g * 64 + lane;
                bool v = p < N;
                float px = v ? pts[(size_t)p * 5 + 0] : 3.0e38f;
                float py = v ? pts[(size_t)p * 5 + 1] : 3.0e38f;
                int c = __popcll(__ballot(pt_in(bx, by, T, px, py)));
                if (lane == 0) s_cnt[g] = c;
                tloc += c;
            }
            if (lane == 0) s_tot[wid] = tloc;  // unconditional (0 if no groups)
            __syncthreads();                   // s_cnt + s_tot visible
            int tsum = 0;
            #pragma unroll
            for (int w = 0; w < 16; ++w) tsum += s_tot[w];
            total += tsum;
            if (total >= S) { ngrp_eff = ghi; break; }   // block-uniform
            __syncthreads();                   // protect s_tot reuse next tier
            glo = ghi;
        }
        if (glo >= ngrp) break;
    }

    // ---- block scan over groups [0, ngrp_eff) ----
    int gpt = (ngrp_eff + 1023) >> 10;         // 1..4
    int g0 = tid * gpt;
    int c[4];
    int tsum = 0;
    #pragma unroll
    for (int i = 0; i < 4; ++i) {
        int g = g0 + i;
        int cv = (i < gpt && g < ngrp_eff) ? s_cnt[g] : 0;
        c[i] = cv; tsum += cv;
    }
    int v = tsum;
    #pragma unroll
    for (int d = 1; d < 64; d <<= 1) {
        int u = __shfl_up(v, d, 64);
        if (lane >= d) v += u;
    }
    if (lane == 63) s_wsum[wid] = v;
    __syncthreads();
    int woff = 0;
    #pragma unroll
    for (int w = 0; w < 16; ++w) if (w < wid) woff += s_wsum[w];
    int base = woff + (v - tsum);              // exclusive prefix of thread's groups

    // ---- worklist: groups with cnt>0 && base<S (<= S entries) ----
    #pragma unroll
    for (int i = 0; i < 4; ++i) {
        if (i < gpt) {
            int g = g0 + i;
            if (g < ngrp_eff) {
                int cnt = c[i];
                if (cnt > 0 && base < S) {
                    int slot = atomicAdd(&s_nwork, 1);
                    s_work[slot] = (base << 16) | g;
                }
                base += cnt;
            }
        }
    }
    __syncthreads();
    int nwork = s_nwork;

    // ---- emission: one wave per worklist entry ----
    for (int i = wid; i < nwork; i += 16) {
        int e = s_work[i];
        int g = e & 0xffff;
        int gbase = e >> 16;
        int p = g * 64 + lane;
        bool in = false;
        float px = 0.f, py = 0.f;
        if (p < N) {
            px = pts[(size_t)p * 5 + 0];
            py = pts[(size_t)p * 5 + 1];
            in = pt_in(bx, by, T, px, py);
        }
        unsigned long long bal = __ballot(in);
        int rank = __popcll(bal & ((1ull << lane) - 1ull));
        int pos = gbase + rank;
        if (in && pos < S) {
            float* o = out + ((size_t)m * S + pos) * 7;
            const float* pp = pts + (size_t)p * 5;
            o[0] = px;    o[1] = py;    o[2] = pp[2];
            o[3] = pp[3]; o[4] = pp[4];
            o[5] = vx;    o[6] = vy;
        }
    }

    // ---- zero-fill tail slots [min(total,S), S) ----
    int cnt = total < S ? total : S;
    size_t outbase = (size_t)m * S * 7;
    for (int i = cnt * 7 + tid; i < S * 7; i += 1024) out[outbase + i] = 0.0f;
}

// ---------------- Fallback: serialized scan (guards failed) ----------------
__device__ float sqrt_le_threshold(float r) {
    float x = __fmul_rn(r, r);
    #pragma unroll 1
    for (int i = 0; i < 16; ++i) {
        float nx = nextafterf(x, INFINITY);
        if (__fsqrt_rn(nx) <= r) x = nx; else break;
    }
    #pragma unroll 1
    for (int i = 0; i < 16; ++i) {
        if (__fsqrt_rn(x) <= r) break;
        x = nextafterf(x, -INFINITY);
    }
    return x;
}

__global__ __launch_bounds__(256) void simple_kernel(
    const float* __restrict__ pts, const float* __restrict__ boxes,
    float* __restrict__ out, int N, int M, int S) {
    __shared__ int s_wc[4];
    int m = blockIdx.x;
    int tid = threadIdx.x;
    int lane = tid & 63;
    int wid = tid >> 6;

    const float* b = boxes + (size_t)m * 9;
    float bx = b[0], by = b[1];
    float T = sqrt_le_threshold(box_radius(b));
    float vx = b[7], vy = b[8];

    int base = 0;
    for (int start = 0; start < N && base < S; start += 256) {
        int p = start + tid;
        bool in = false;
        if (p < N) {
            float px = pts[(size_t)p * 5 + 0];
            float py = pts[(size_t)p * 5 + 1];
            in = pt_in(bx, by, T, px, py);
        }
        unsigned long long bal = __ballot(in);
        if (lane == 0) s_wc[wid] = __popcll(bal);
        __syncthreads();
        int off = 0;
        for (int w = 0; w < wid; ++w) off += s_wc[w];
        int pos = base + off + __popcll(bal & ((1ull << lane) - 1ull));
        if (in && pos < S) {
            float* o = out + ((size_t)m * S + pos) * 7;
            const float* pp = pts + (size_t)p * 5;
            o[0] = pp[0]; o[1] = pp[1]; o[2] = pp[2];
            o[3] = pp[3]; o[4] = pp[4];
            o[5] = vx;    o[6] = vy;
        }
        base += s_wc[0] + s_wc[1] + s_wc[2] + s_wc[3];
        __syncthreads();
    }

    int cnt = base < S ? base : S;
    size_t outbase = (size_t)m * S * 7;
    for (int i = cnt * 7 + tid; i < S * 7; i += 256) out[outbase + i] = 0.0f;
}

extern "C" void kernel_launch(void* const* d_in, const int* in_sizes, int n_in,
                              void* d_out, int out_size, void* d_ws, size_t ws_size,
                              hipStream_t stream) {
    const float* pts = (const float*)d_in[0];
    const float* boxes = (const float*)d_in[1];
    float* out = (float*)d_out;

    int N = in_sizes[0] / 5;
    int M = in_sizes[1] / 9;
    int S = out_size / (M * 7);
    int ngrp = (N + 63) / 64;

    if (S >= 1 && S <= 8192 && ngrp <= MAXGRP) {
        size_t lds = (size_t)(S + 64) * sizeof(int);
        fused_kernel<<<M, 1024, lds, stream>>>(pts, boxes, out, N, M, S, ngrp);
    } else {
        simple_kernel<<<M, 256, 0, stream>>>(pts, boxes, out, N, M, S);
    }
}

// Round 10
// 29.408 us; speedup vs baseline: 3.8456x; 3.8456x over previous
//
#include <hip/hip_runtime.h>
#include <hip/hip_bf16.h>
#include <math.h>

// Cylindrical pooling: for each box, select first S in-radius points (ascending
// index), append box velocity, zero remaining slots.
//
// Exact f32 semantics: dis = sqrt_rn(dx*dx + dy*dy) (explicit _rn, no FMA) and
// dis <= r  <=>  d2 <= T, T = max{x : sqrt_rn(x) <= r} via 64-lane ulp probe
// (bit-exact, validated R7/R8).
//
// Three-dispatch plan, NO cross-block communication (R5: fences ~300us;
// R9: relaxed-atomic hand-off races). Kernel boundaries are the only sync.
//  A: per box, tier-1 counts (groups [0,128) = first 8192 pts), params+total.
//     ~93% of boxes saturate (>= S hits) in tier 1 on gaussian data.
//  B: two INDEPENDENT block roles in one dispatch:
//     - tile blocks: point-parallel counting of groups [128, ngrp) for
//       unsaturated boxes only (plain stores; consumer is dispatch C).
//     - sat-emit blocks: emit saturated boxes now (depends only on A),
//       overlapping the tile counting.
//  C: unsaturated boxes only: scan all counts, worklist, emit, tail-fill.
//     Saturated blocks exit after one load.
// Distribution affects speed only; worst case = all boxes unsaturated ->
// B degenerates to pure counting, C does all emission (R4 behavior).

#define P0GRP 128   // tier-1 groups (64 points each)

__device__ __forceinline__ float box_radius(const float* __restrict__ b) {
    float hx = __fmul_rn(b[3], 0.5f);
    float hy = __fmul_rn(b[4], 0.5f);
    float nrm = __fsqrt_rn(__fadd_rn(__fmul_rn(hx, hx), __fmul_rn(hy, hy)));
    return __fmul_rn(nrm, 1.1f);   // GAMMA
}

// largest x with __fsqrt_rn(x) <= r, searched in a 64-ulp window around r*r.
// All 64 lanes participate (call under wave-uniform control flow).
__device__ __forceinline__ float probe_T(float r, int lane) {
    int xb = __float_as_int(__fmul_rn(r, r));      // r >= 0 so xb >= 0
    int yb = xb + lane - 32; if (yb < 0) yb = 0;
    bool ok = __fsqrt_rn(__int_as_float(yb)) <= r; // monotone in yb
    unsigned long long mask = __ballot(ok);
    int hi = 63 - __clzll(mask);
    int tb = xb + hi - 32; if (tb < 0) tb = 0;
    return __int_as_float(tb);
}

__device__ __forceinline__ bool pt_in(float bx, float by, float T,
                                      float px, float py) {
    float dx = __fsub_rn(bx, px);
    float dy = __fsub_rn(by, py);
    float d2 = __fadd_rn(__fmul_rn(dx, dx), __fmul_rn(dy, dy));
    return d2 <= T;
}

// ---------------- A: tier-1 counts for ALL boxes + params ----------------
// Grid: M blocks x 1024 threads.
__global__ __launch_bounds__(1024) void kernelA(
    const float* __restrict__ pts, const float* __restrict__ boxes,
    int* __restrict__ counts, float4* __restrict__ bprep,
    int N, int M, int ngrp, int ngrpA) {
    __shared__ int s_tot[16];
    int m = blockIdx.x;
    int tid = threadIdx.x;
    int lane = tid & 63;
    int wid = tid >> 6;

    const float* b = boxes + (size_t)m * 9;
    float bx = b[0], by = b[1];
    float T = probe_T(box_radius(b), lane);

    int tot = 0;
    for (int g = wid; g < ngrpA; g += 16) {
        int p = g * 64 + lane;
        bool v = p < N;
        float px = v ? pts[(size_t)p * 5 + 0] : 3.0e38f;
        float py = v ? pts[(size_t)p * 5 + 1] : 3.0e38f;
        int c = __popcll(__ballot(pt_in(bx, by, T, px, py)));
        if (lane == 0) counts[(size_t)m * ngrp + g] = c;
        tot += c;
    }
    if (lane == 0) s_tot[wid] = tot;
    __syncthreads();
    if (tid == 0) {
        int total = 0;
        #pragma unroll
        for (int w = 0; w < 16; ++w) total += s_tot[w];
        bprep[m] = make_float4(bx, by, T, __int_as_float(total));
    }
}

// ---------------- B: tile counting (unsat) || sat emission ----------------
// Grid: TB tile blocks then M sat-emit blocks, 256 threads each.
// The two roles are fully independent (sat-emit depends only on kernelA).
__global__ __launch_bounds__(256) void kernelB(
    const float* __restrict__ pts, const float* __restrict__ boxes,
    const float4* __restrict__ bprep, int* __restrict__ counts,
    float* __restrict__ out,
    int N, int M, int S, int ngrp, int ngrpA, int ntile, int mchunk, int TB) {
    extern __shared__ int s_work[];        // S + 64 entries
    __shared__ float4 s_box[64];
    __shared__ unsigned long long s_mask;
    __shared__ int s_ws[4];
    __shared__ int s_nwork;

    int bid = blockIdx.x;
    int tid = threadIdx.x;
    int lane = tid & 63;
    int wid = tid >> 6;

    if (bid < TB) {
        // ---- tile role: count groups [ngrpA, ngrp) for unsat boxes ----
        int tile = bid % ntile;
        int mc = bid / ntile;
        int m0 = mc * mchunk;
        int nmb = M - m0; if (nmb > mchunk) nmb = mchunk;   // mchunk <= 64

        bool act = false;
        if (tid < nmb) {
            float4 bb = bprep[m0 + tid];
            s_box[tid] = bb;
            act = __float_as_int(bb.w) < S;
        }
        unsigned long long bal = __ballot(act);   // wave 0 holds true mask
        if (tid == 0) s_mask = bal;
        __syncthreads();
        unsigned long long amask = s_mask;
        if (amask == 0) return;                   // block-uniform

        int pbase = ngrpA * 64 + tile * 1024 + wid * 256;
        int g0 = pbase >> 6;
        if (g0 >= ngrp) return;                   // wave-uniform; no syncs below
        bool vec4 = (g0 + 4 <= ngrp);

        float px[4], py[4];
        #pragma unroll
        for (int i = 0; i < 4; ++i) {
            int p = pbase + i * 64 + lane;
            bool v = p < N;
            px[i] = v ? pts[(size_t)p * 5 + 0] : 3.0e38f;
            py[i] = v ? pts[(size_t)p * 5 + 1] : 3.0e38f;
        }
        while (amask) {
            int mm = __builtin_ctzll(amask);
            amask &= amask - 1;
            float4 bb = s_box[mm];
            int cnt[4];
            #pragma unroll
            for (int i = 0; i < 4; ++i)
                cnt[i] = __popcll(__ballot(pt_in(bb.x, bb.y, bb.z,
                                                 px[i], py[i])));
            if (lane == 0) {
                int* dst = counts + (size_t)(m0 + mm) * ngrp + g0;
                if (vec4) {
                    *reinterpret_cast<int4*>(dst) =
                        make_int4(cnt[0], cnt[1], cnt[2], cnt[3]);
                } else {
                    #pragma unroll
                    for (int i = 0; i < 4; ++i)
                        if (g0 + i < ngrp) dst[i] = cnt[i];
                }
            }
        }
        return;
    }

    // ---- sat-emit role: one block per box; unsat boxes exit (C handles) ----
    int m = bid - TB;
    float4 bb = bprep[m];
    int satA = __float_as_int(bb.w);
    if (satA < S) return;                  // unsaturated -> dispatch C

    if (tid == 0) s_nwork = 0;
    float bx = bb.x, by = bb.y, T = bb.z;
    float vx = boxes[(size_t)m * 9 + 7];
    float vy = boxes[(size_t)m * 9 + 8];
    const int* my_counts = counts + (size_t)m * ngrp;

    // ngrpA <= 128 <= 256 threads: one group per thread
    int c = (tid < ngrpA) ? my_counts[tid] : 0;
    int v = c;
    #pragma unroll
    for (int d = 1; d < 64; d <<= 1) {
        int u = __shfl_up(v, d, 64);
        if (lane >= d) v += u;
    }
    if (lane == 63) s_ws[wid] = v;
    __syncthreads();
    int woff = 0;
    #pragma unroll
    for (int w = 0; w < 4; ++w) if (w < wid) woff += s_ws[w];
    int base = woff + (v - c);             // exclusive prefix of this group

    if (tid < ngrpA && c > 0 && base < S) {
        int slot = atomicAdd(&s_nwork, 1);
        s_work[slot] = (base << 16) | tid;
    }
    __syncthreads();
    int nwork = s_nwork;

    for (int i = wid; i < nwork; i += 4) {
        int e = s_work[i];
        int g = e & 0xffff;
        int gbase = e >> 16;
        int p = g * 64 + lane;
        bool in = false;
        float px = 0.f, py = 0.f;
        if (p < N) {
            px = pts[(size_t)p * 5 + 0];
            py = pts[(size_t)p * 5 + 1];
            in = pt_in(bx, by, T, px, py);
        }
        unsigned long long bal = __ballot(in);
        int rank = __popcll(bal & ((1ull << lane) - 1ull));
        int pos = gbase + rank;
        if (in && pos < S) {
            float* o = out + ((size_t)m * S + pos) * 7;
            const float* pp = pts + (size_t)p * 5;
            o[0] = px;    o[1] = py;    o[2] = pp[2];
            o[3] = pp[3]; o[4] = pp[4];
            o[5] = vx;    o[6] = vy;
        }
    }
    // saturated: total >= S, all S slots written, no tail-fill needed
}

// ---------------- C: emission for unsaturated boxes only ----------------
// Grid: M blocks x 1024 threads. Saturated blocks exit after one load.
__global__ __launch_bounds__(1024) void kernelC(
    const float* __restrict__ pts, const float* __restrict__ boxes,
    const float4* __restrict__ bprep,
    const int* __restrict__ counts, float* __restrict__ out,
    int N, int M, int S, int ngrp) {
    extern __shared__ int s_work[];        // S + 64 entries
    __shared__ int s_wsum[16];
    __shared__ int s_nwork;

    int m = blockIdx.x;
    float4 bb = bprep[m];
    int satA = __float_as_int(bb.w);
    if (satA >= S) return;                 // emitted by kernelB

    int tid = threadIdx.x;
    int lane = tid & 63;
    int wid = tid >> 6;

    if (tid == 0) s_nwork = 0;
    float bx = bb.x, by = bb.y, T = bb.z;
    float vx = boxes[(size_t)m * 9 + 7];
    float vy = boxes[(size_t)m * 9 + 8];

    const int* my_counts = counts + (size_t)m * ngrp;
    int gpt = (ngrp + 1023) >> 10;         // <= 4 (launcher guard)
    int g0 = tid * gpt;

    int c[4];
    int tsum = 0;
    if (gpt == 4 && ((ngrp & 3) == 0) && g0 + 3 < ngrp) {
        int4 v4 = *reinterpret_cast<const int4*>(my_counts + g0);
        c[0] = v4.x; c[1] = v4.y; c[2] = v4.z; c[3] = v4.w;
        tsum = c[0] + c[1] + c[2] + c[3];
    } else {
        #pragma unroll
        for (int i = 0; i < 4; ++i) {
            int g = g0 + i;
            c[i] = (i < gpt && g < ngrp) ? my_counts[g] : 0;
            tsum += c[i];
        }
    }

    int v = tsum;
    #pragma unroll
    for (int d = 1; d < 64; d <<= 1) {
        int u = __shfl_up(v, d, 64);
        if (lane >= d) v += u;
    }
    if (lane == 63) s_wsum[wid] = v;
    __syncthreads();

    int woff = 0, total = 0;
    #pragma unroll
    for (int w = 0; w < 16; ++w) {
        int s = s_wsum[w];
        total += s;
        if (w < wid) woff += s;
    }
    int base = woff + (v - tsum);          // exclusive prefix of thread's groups

    #pragma unroll
    for (int i = 0; i < 4; ++i) {
        if (i < gpt) {
            int g = g0 + i;
            if (g < ngrp) {
                int cnt = c[i];
                if (cnt > 0 && base < S) {
                    int slot = atomicAdd(&s_nwork, 1);
                    s_work[slot] = (base << 16) | g;
                }
                base += cnt;
            }
        }
    }
    __syncthreads();
    int nwork = s_nwork;

    for (int i = wid; i < nwork; i += 16) {
        int e = s_work[i];
        int g = e & 0xffff;
        int gbase = e >> 16;
        int p = g * 64 + lane;
        bool in = false;
        float px = 0.f, py = 0.f;
        if (p < N) {
            px = pts[(size_t)p * 5 + 0];
            py = pts[(size_t)p * 5 + 1];
            in = pt_in(bx, by, T, px, py);
        }
        unsigned long long bal = __ballot(in);
        int rank = __popcll(bal & ((1ull << lane) - 1ull));
        int pos = gbase + rank;
        if (in && pos < S) {
            float* o = out + ((size_t)m * S + pos) * 7;
            const float* pp = pts + (size_t)p * 5;
            o[0] = px;    o[1] = py;    o[2] = pp[2];
            o[3] = pp[3]; o[4] = pp[4];
            o[5] = vx;    o[6] = vy;
        }
    }

    // zero-fill tail slots [min(total,S), S)
    int cnt = total < S ? total : S;
    size_t outbase = (size_t)m * S * 7;
    for (int i = cnt * 7 + tid; i < S * 7; i += 1024) out[outbase + i] = 0.0f;
}

// ---------------- Fallback: serialized scan (guards failed) ----------------
__device__ float sqrt_le_threshold(float r) {
    float x = __fmul_rn(r, r);
    #pragma unroll 1
    for (int i = 0; i < 16; ++i) {
        float nx = nextafterf(x, INFINITY);
        if (__fsqrt_rn(nx) <= r) x = nx; else break;
    }
    #pragma unroll 1
    for (int i = 0; i < 16; ++i) {
        if (__fsqrt_rn(x) <= r) break;
        x = nextafterf(x, -INFINITY);
    }
    return x;
}

__global__ __launch_bounds__(256) void simple_kernel(
    const float* __restrict__ pts, const float* __restrict__ boxes,
    float* __restrict__ out, int N, int M, int S) {
    __shared__ int s_wc[4];
    int m = blockIdx.x;
    int tid = threadIdx.x;
    int lane = tid & 63;
    int wid = tid >> 6;

    const float* b = boxes + (size_t)m * 9;
    float bx = b[0], by = b[1];
    float T = sqrt_le_threshold(box_radius(b));
    float vx = b[7], vy = b[8];

    int base = 0;
    for (int start = 0; start < N && base < S; start += 256) {
        int p = start + tid;
        bool in = false;
        if (p < N) {
            float px = pts[(size_t)p * 5 + 0];
            float py = pts[(size_t)p * 5 + 1];
            in = pt_in(bx, by, T, px, py);
        }
        unsigned long long bal = __ballot(in);
        if (lane == 0) s_wc[wid] = __popcll(bal);
        __syncthreads();
        int off = 0;
        for (int w = 0; w < wid; ++w) off += s_wc[w];
        int pos = base + off + __popcll(bal & ((1ull << lane) - 1ull));
        if (in && pos < S) {
            float* o = out + ((size_t)m * S + pos) * 7;
            const float* pp = pts + (size_t)p * 5;
            o[0] = pp[0]; o[1] = pp[1]; o[2] = pp[2];
            o[3] = pp[3]; o[4] = pp[4];
            o[5] = vx;    o[6] = vy;
        }
        base += s_wc[0] + s_wc[1] + s_wc[2] + s_wc[3];
        __syncthreads();
    }

    int cnt = base < S ? base : S;
    size_t outbase = (size_t)m * S * 7;
    for (int i = cnt * 7 + tid; i < S * 7; i += 256) out[outbase + i] = 0.0f;
}

extern "C" void kernel_launch(void* const* d_in, const int* in_sizes, int n_in,
                              void* d_out, int out_size, void* d_ws, size_t ws_size,
                              hipStream_t stream) {
    const float* pts = (const float*)d_in[0];
    const float* boxes = (const float*)d_in[1];
    float* out = (float*)d_out;

    int N = in_sizes[0] / 5;
    int M = in_sizes[1] / 9;
    int S = out_size / (M * 7);
    int ngrp = (N + 63) / 64;
    int ngrpA = ngrp < P0GRP ? ngrp : P0GRP;

    size_t counts_bytes = ((size_t)M * ngrp * sizeof(int) + 15) & ~(size_t)15;
    size_t need = counts_bytes + (size_t)M * sizeof(float4);

    if (ws_size >= need && S >= 1 && S < 32768 && ngrp <= 4096 && M <= 65535) {
        int* counts = (int*)d_ws;
        float4* bprep = (float4*)((char*)d_ws + counts_bytes);
        size_t lds = (size_t)(S + 64) * sizeof(int);

        kernelA<<<M, 1024, 0, stream>>>(pts, boxes, counts, bprep,
                                        N, M, ngrp, ngrpA);

        int ntile = 0, mchunk = 1, TB = 0;
        if (ngrp > ngrpA) {
            ntile = (ngrp - ngrpA + 15) / 16;     // 16 groups (1024 pts)/tile
            int msplit = 2048 / ntile;
            if (msplit < 1) msplit = 1;
            if (msplit > M) msplit = M;
            mchunk = (M + msplit - 1) / msplit;
            if (mchunk > 64) mchunk = 64;
            msplit = (M + mchunk - 1) / mchunk;
            TB = ntile * msplit;
        }
        kernelB<<<TB + M, 256, lds, stream>>>(pts, boxes, bprep, counts, out,
                                              N, M, S, ngrp, ngrpA,
                                              ntile, mchunk, TB);

        kernelC<<<M, 1024, lds, stream>>>(pts, boxes, bprep, counts, out,
                                          N, M, S, ngrp);
    } else {
        simple_kernel<<<M, 256, 0, stream>>>(pts, boxes, out, N, M, S);
    }
}

// Round 11
// 24.011 us; speedup vs baseline: 4.7100x; 1.2248x over previous
//
#include <hip/hip_runtime.h>
#include <hip/hip_bf16.h>
#include <math.h>

// Cylindrical pooling: for each box, select first S in-radius points (ascending
// index), append box velocity, zero remaining slots.
//
// Exact f32 semantics: dis = sqrt_rn(dx*dx + dy*dy) (explicit _rn, no FMA) and
// dis <= r  <=>  d2 <= T, T = max{x : sqrt_rn(x) <= r} via 64-lane ulp probe
// (bit-exact, cross-validated R7/R8/R10).
//
// R4 structure (empirically best: 24.6us; sat-emit placement in A=27.0,
// B=29.4, C=24.6; cross-block sync forbidden: fences ~300us (R5), relaxed
// atomics race (R9); unsat sweep must be multi-CU (R8: single-CU L2-BW-bound)):
//  A: per box, tier-1 counts (groups [0,128) = first 8192 pts) + params+total.
//  B: point-parallel counts of groups [128, ngrp) for unsaturated boxes only.
//  C: all-box emission: scan ngrp_eff counts, worklist, emit, tail-fill.
// Kernel boundaries are the only synchronization.

#define P0GRP 128   // tier-1 groups (64 points each)

__device__ __forceinline__ float box_radius(const float* __restrict__ b) {
    float hx = __fmul_rn(b[3], 0.5f);
    float hy = __fmul_rn(b[4], 0.5f);
    float nrm = __fsqrt_rn(__fadd_rn(__fmul_rn(hx, hx), __fmul_rn(hy, hy)));
    return __fmul_rn(nrm, 1.1f);   // GAMMA
}

// largest x with __fsqrt_rn(x) <= r, searched in a 64-ulp window around r*r.
// All 64 lanes participate (call under wave-uniform control flow).
__device__ __forceinline__ float probe_T(float r, int lane) {
    int xb = __float_as_int(__fmul_rn(r, r));      // r >= 0 so xb >= 0
    int yb = xb + lane - 32; if (yb < 0) yb = 0;
    bool ok = __fsqrt_rn(__int_as_float(yb)) <= r; // monotone in yb
    unsigned long long mask = __ballot(ok);
    int hi = 63 - __clzll(mask);
    int tb = xb + hi - 32; if (tb < 0) tb = 0;
    return __int_as_float(tb);
}

__device__ __forceinline__ bool pt_in(float bx, float by, float T,
                                      float px, float py) {
    float dx = __fsub_rn(bx, px);
    float dy = __fsub_rn(by, py);
    float d2 = __fadd_rn(__fmul_rn(dx, dx), __fmul_rn(dy, dy));
    return d2 <= T;
}

// ---------------- Kernel A: params + tier-1 counts + saturation total ------
// Grid: M blocks x 1024 threads. Box m: count groups [0, ngrpA), store counts,
// block-reduce total -> bprep[m] = (bx, by, T, bits(total)).
__global__ __launch_bounds__(1024) void countA_kernel(
    const float* __restrict__ pts, const float* __restrict__ boxes,
    int* __restrict__ counts, float4* __restrict__ bprep,
    int N, int M, int ngrp, int ngrpA) {
    __shared__ int s_tot[16];
    int m = blockIdx.x;
    int tid = threadIdx.x;
    int lane = tid & 63;
    int wid = tid >> 6;

    const float* b = boxes + (size_t)m * 9;
    float bx = b[0], by = b[1];
    float T = probe_T(box_radius(b), lane);

    int tot = 0;
    #pragma unroll 2
    for (int g = wid; g < ngrpA; g += 16) {
        int p = g * 64 + lane;
        bool v = p < N;
        float px = v ? pts[(size_t)p * 5 + 0] : 3.0e38f;
        float py = v ? pts[(size_t)p * 5 + 1] : 3.0e38f;
        int c = __popcll(__ballot(pt_in(bx, by, T, px, py)));
        if (lane == 0) counts[(size_t)m * ngrp + g] = c;
        tot += c;
    }
    if (lane == 0) s_tot[wid] = tot;
    __syncthreads();
    if (tid == 0) {
        int total = 0;
        #pragma unroll
        for (int w = 0; w < 16; ++w) total += s_tot[w];
        bprep[m] = make_float4(bx, by, T, __int_as_float(total));
    }
}

// ---------------- Kernel B: remaining counts for unsaturated boxes ----------
// Grid: ntile x msplit blocks, 256 threads. Each wave holds 256 points of
// groups [ngrpA..); per <=64-box chunk, only boxes with satA < S are counted.
__global__ __launch_bounds__(256) void countB_kernel(
    const float* __restrict__ pts, const float4* __restrict__ bprep,
    int* __restrict__ counts, int N, int M, int S, int ngrp, int ngrpA,
    int ntile, int mchunk) {
    __shared__ float4 s_box[64];
    __shared__ unsigned long long s_mask;
    int tid = threadIdx.x;
    int lane = tid & 63;
    int wid = tid >> 6;

    int tile = blockIdx.x % ntile;
    int mc = blockIdx.x / ntile;
    int m0 = mc * mchunk;
    int nmb = M - m0; if (nmb > mchunk) nmb = mchunk;   // mchunk <= 64

    bool act = false;
    if (tid < nmb) {
        float4 bb = bprep[m0 + tid];
        s_box[tid] = bb;
        act = __float_as_int(bb.w) < S;
    }
    unsigned long long bal = __ballot(act);   // wave 0 holds the real mask
    if (tid == 0) s_mask = bal;
    __syncthreads();
    unsigned long long amask = s_mask;
    if (amask == 0) return;                   // block-uniform

    int pbase = ngrpA * 64 + tile * 1024 + wid * 256;
    int g0 = pbase >> 6;
    if (g0 >= ngrp) return;                   // wave-uniform, no syncs below
    bool vec4 = (g0 + 4 <= ngrp);

    float px[4], py[4];
    #pragma unroll
    for (int i = 0; i < 4; ++i) {
        int p = pbase + i * 64 + lane;
        bool v = p < N;
        px[i] = v ? pts[(size_t)p * 5 + 0] : 3.0e38f;
        py[i] = v ? pts[(size_t)p * 5 + 1] : 3.0e38f;
    }

    while (amask) {
        int mm = __builtin_ctzll(amask);
        amask &= amask - 1;
        float4 bb = s_box[mm];
        int cnt[4];
        #pragma unroll
        for (int i = 0; i < 4; ++i)
            cnt[i] = __popcll(__ballot(pt_in(bb.x, bb.y, bb.z, px[i], py[i])));
        if (lane == 0) {
            int* dst = counts + (size_t)(m0 + mm) * ngrp + g0;
            if (vec4) {
                *reinterpret_cast<int4*>(dst) =
                    make_int4(cnt[0], cnt[1], cnt[2], cnt[3]);
            } else {
                #pragma unroll
                for (int i = 0; i < 4; ++i)
                    if (g0 + i < ngrp) dst[i] = cnt[i];
            }
        }
    }
}

// ---------------- Kernel C: per-box scan + worklist + emission ----------------
// Grid: M blocks x 1024 threads. Scan only ngrp_eff groups (P0GRP if the box
// saturated in tier 1), build worklist of groups with count>0 && base<S,
// waves emit worklist entries.
__global__ __launch_bounds__(1024) void emit_kernel(
    const float* __restrict__ pts, const float* __restrict__ boxes,
    const float4* __restrict__ bprep,
    const int* __restrict__ counts, float* __restrict__ out,
    int N, int M, int S, int ngrp, int ngrpA) {
    extern __shared__ int s_work[];        // S + 64 entries
    __shared__ int s_wsum[16];
    __shared__ int s_nwork;

    int m = blockIdx.x;
    int tid = threadIdx.x;
    int lane = tid & 63;
    int wid = tid >> 6;
    int nw = blockDim.x >> 6;              // 16

    if (tid == 0) s_nwork = 0;

    float4 bb = bprep[m];
    float bx = bb.x, by = bb.y, T = bb.z;
    int satA = __float_as_int(bb.w);
    int ngrp_eff = (satA >= S) ? ngrpA : ngrp;
    float vx = boxes[(size_t)m * 9 + 7];
    float vy = boxes[(size_t)m * 9 + 8];

    const int* my_counts = counts + (size_t)m * ngrp;
    int gpt = (ngrp_eff + blockDim.x - 1) / blockDim.x;   // 1 or 4 typically
    int g0 = tid * gpt;

    int c[8];                               // gpt <= 8 guaranteed by launcher
    int tsum = 0;
    if (gpt == 4 && (g0 & 3) == 0 && g0 + 3 < ngrp_eff) {
        int4 v4 = *reinterpret_cast<const int4*>(my_counts + g0);
        c[0] = v4.x; c[1] = v4.y; c[2] = v4.z; c[3] = v4.w;
        tsum = c[0] + c[1] + c[2] + c[3];
    } else {
        #pragma unroll
        for (int i = 0; i < 8; ++i) {
            int g = g0 + i;
            c[i] = (i < gpt && g < ngrp_eff) ? my_counts[g] : 0;
            tsum += c[i];
        }
    }

    // wave-inclusive scan of tsum
    int v = tsum;
    #pragma unroll
    for (int d = 1; d < 64; d <<= 1) {
        int u = __shfl_up(v, d, 64);
        if (lane >= d) v += u;
    }
    if (lane == 63) s_wsum[wid] = v;
    __syncthreads();

    int woff = 0, total = 0;
    for (int w = 0; w < nw; ++w) {
        int s = s_wsum[w];
        total += s;
        if (w < wid) woff += s;
    }
    int base = woff + (v - tsum);          // exclusive prefix of thread's first group

    // worklist build: order within list irrelevant (positions precomputed)
    for (int i = 0; i < gpt; ++i) {
        int cnt = c[i];
        if (cnt > 0 && base < S) {
            int slot = atomicAdd(&s_nwork, 1);
            s_work[slot] = (base << 16) | (g0 + i);
        }
        base += cnt;
    }
    __syncthreads();
    int nwork = s_nwork;

    // emission: one wave per worklist entry
    for (int i = wid; i < nwork; i += nw) {
        int e = s_work[i];
        int g = e & 0xffff;
        int gbase = e >> 16;
        int p = g * 64 + lane;
        bool in = false;
        float px = 0.f, py = 0.f;
        if (p < N) {
            px = pts[(size_t)p * 5 + 0];
            py = pts[(size_t)p * 5 + 1];
            in = pt_in(bx, by, T, px, py);
        }
        unsigned long long bal = __ballot(in);
        int rank = __popcll(bal & ((1ull << lane) - 1ull));
        int pos = gbase + rank;
        if (in && pos < S) {
            float* o = out + ((size_t)m * S + pos) * 7;
            const float* pp = pts + (size_t)p * 5;
            o[0] = px;    o[1] = py;    o[2] = pp[2];
            o[3] = pp[3]; o[4] = pp[4];
            o[5] = vx;    o[6] = vy;
        }
    }

    // zero-fill tail slots [min(total,S), S) — empty for saturated boxes
    int cnt = total < S ? total : S;
    size_t outbase = (size_t)m * S * 7;
    for (int i = cnt * 7 + tid; i < S * 7; i += blockDim.x) out[outbase + i] = 0.0f;
}

// ---------------- Fallback: serialized scan (guards failed) ----------------
__device__ float sqrt_le_threshold(float r) {
    float x = __fmul_rn(r, r);
    #pragma unroll 1
    for (int i = 0; i < 16; ++i) {
        float nx = nextafterf(x, INFINITY);
        if (__fsqrt_rn(nx) <= r) x = nx; else break;
    }
    #pragma unroll 1
    for (int i = 0; i < 16; ++i) {
        if (__fsqrt_rn(x) <= r) break;
        x = nextafterf(x, -INFINITY);
    }
    return x;
}

__global__ __launch_bounds__(256) void simple_kernel(
    const float* __restrict__ pts, const float* __restrict__ boxes,
    float* __restrict__ out, int N, int M, int S) {
    __shared__ int s_wc[4];
    int m = blockIdx.x;
    int tid = threadIdx.x;
    int lane = tid & 63;
    int wid = tid >> 6;

    const float* b = boxes + (size_t)m * 9;
    float bx = b[0], by = b[1];
    float T = sqrt_le_threshold(box_radius(b));
    float vx = b[7], vy = b[8];

    int base = 0;
    for (int start = 0; start < N && base < S; start += 256) {
        int p = start + tid;
        bool in = false;
        if (p < N) {
            float px = pts[(size_t)p * 5 + 0];
            float py = pts[(size_t)p * 5 + 1];
            in = pt_in(bx, by, T, px, py);
        }
        unsigned long long bal = __ballot(in);
        if (lane == 0) s_wc[wid] = __popcll(bal);
        __syncthreads();
        int off = 0;
        for (int w = 0; w < wid; ++w) off += s_wc[w];
        int pos = base + off + __popcll(bal & ((1ull << lane) - 1ull));
        if (in && pos < S) {
            float* o = out + ((size_t)m * S + pos) * 7;
            const float* pp = pts + (size_t)p * 5;
            o[0] = pp[0]; o[1] = pp[1]; o[2] = pp[2];
            o[3] = pp[3]; o[4] = pp[4];
            o[5] = vx;    o[6] = vy;
        }
        base += s_wc[0] + s_wc[1] + s_wc[2] + s_wc[3];
        __syncthreads();
    }

    int cnt = base < S ? base : S;
    size_t outbase = (size_t)m * S * 7;
    for (int i = cnt * 7 + tid; i < S * 7; i += 256) out[outbase + i] = 0.0f;
}

extern "C" void kernel_launch(void* const* d_in, const int* in_sizes, int n_in,
                              void* d_out, int out_size, void* d_ws, size_t ws_size,
                              hipStream_t stream) {
    const float* pts = (const float*)d_in[0];
    const float* boxes = (const float*)d_in[1];
    float* out = (float*)d_out;

    int N = in_sizes[0] / 5;
    int M = in_sizes[1] / 9;
    int S = out_size / (M * 7);
    int ngrp = (N + 63) / 64;
    int ngrpA = ngrp < P0GRP ? ngrp : P0GRP;

    size_t counts_bytes = ((size_t)M * ngrp * sizeof(int) + 15) & ~(size_t)15;
    size_t need = counts_bytes + (size_t)M * sizeof(float4);
    int gpt = (ngrp + 1023) / 1024;

    if (ws_size >= need && gpt <= 8 && S >= 1 && S < 32768 && ngrp < 65536
        && M <= 65535) {
        int* counts = (int*)d_ws;
        float4* bprep = (float4*)((char*)d_ws + counts_bytes);

        countA_kernel<<<M, 1024, 0, stream>>>(pts, boxes, counts, bprep,
                                              N, M, ngrp, ngrpA);

        if (ngrp > ngrpA) {
            int ntile = (ngrp - ngrpA + 15) / 16;   // 16 groups (1024 pts)/tile
            int msplit = 2048 / ntile;
            if (msplit < 1) msplit = 1;
            if (msplit > M) msplit = M;
            int mchunk = (M + msplit - 1) / msplit;
            if (mchunk > 64) mchunk = 64;
            msplit = (M + mchunk - 1) / mchunk;
            countB_kernel<<<ntile * msplit, 256, 0, stream>>>(
                pts, bprep, counts, N, M, S, ngrp, ngrpA, ntile, mchunk);
        }

        size_t lds = (size_t)(S + 64) * sizeof(int);
        emit_kernel<<<M, 1024, lds, stream>>>(pts, boxes, bprep, counts, out,
                                              N, M, S, ngrp, ngrpA);
    } else {
        simple_kernel<<<M, 256, 0, stream>>>(pts, boxes, out, N, M, S);
    }
}